// Round 1
// baseline (159.790 us; speedup 1.0000x reference)
//
#include <hip/hip_runtime.h>

namespace {

constexpr int Bn    = 10;
constexpr int H     = 320;
constexpr int W     = 1024;
constexpr int PTS   = 500;
constexpr int DENSE = 2000;
constexpr int N     = Bn * PTS;   // 5000 rows
constexpr int HWp   = H * W;

// One 64-thread block (1 wave) per output row.
// Each thread holds 32 samples in registers (statically indexed).
__global__ __launch_bounds__(64, 4)
void rsbsp_kernel(const float* __restrict__ disp,
                  const float* __restrict__ forepred,
                  const int*   __restrict__ centerx,
                  const int*   __restrict__ centery,
                  const int*   __restrict__ bx,
                  const int*   __restrict__ by,
                  float*       __restrict__ out)
{
    const int row  = blockIdx.x;      // 0..4999
    const int lane = threadIdx.x;     // 0..63
    const int b    = row / PTS;       // channelInd
    const int cx   = centerx[row];
    const int cy   = centery[row];
    const float* db = disp     + b * HWp;
    const float* fb = forepred + b * HWp;

    // ---- validRow: 3x3 maxpool of |sobel_x(forepred)| at center, * (disp>0.007),
    //      clamp(min=3)-3, > 0.1. Centers are >=11 from every border, so SAME
    //      padding and the 4-pixel border zeroing are unreachable.
    //      Computed redundantly by all 64 lanes (uniform addresses -> 1 txn each).
    float F[5][5];
    #pragma unroll
    for (int a = 0; a < 5; ++a)
        #pragma unroll
        for (int c = 0; c < 5; ++c)
            F[a][c] = fb[(cy - 2 + a) * W + (cx - 2 + c)];

    float v = 0.f;
    #pragma unroll
    for (int dy = 0; dy < 3; ++dy)
        #pragma unroll
        for (int dx = 0; dx < 3; ++dx) {
            const float g = (F[dy    ][dx + 2] - F[dy    ][dx])
                    + 2.f * (F[dy + 1][dx + 2] - F[dy + 1][dx])
                    +       (F[dy + 2][dx + 2] - F[dy + 2][dx]);
            v = fmaxf(v, fabsf(g));
        }
    const float dcen = db[cy * W + cx];
    const float mgv  = fmaxf(v * ((dcen > 0.007f) ? 1.f : 0.f), 3.f) - 3.f;
    const bool validRow = mgv > 0.1f;

    // ---- gather 2000 samples; bx/by loaded as int4 (coalesced 16B/lane).
    // Row offset 2000*4B = 8000B is 16B-aligned.
    const int4* bx4 = reinterpret_cast<const int4*>(bx + row * DENSE);
    const int4* by4 = reinterpret_cast<const int4*>(by + row * DENSE);
    const int cbase = cy * W + cx;

    float s[32];
    float mx = -INFINITY, mn = INFINITY;
    #pragma unroll
    for (int k = 0; k < 8; ++k) {
        const int q = lane + 64 * k;           // int4 index, 500 total
        if (q < DENSE / 4) {                    // only k==7 partially masked
            const int4 xb = bx4[q];
            const int4 yb = by4[q];
            const float x0 = db[cbase + yb.x * W + xb.x];
            const float x1 = db[cbase + yb.y * W + xb.y];
            const float x2 = db[cbase + yb.z * W + xb.z];
            const float x3 = db[cbase + yb.w * W + xb.w];
            s[k * 4 + 0] = x0; s[k * 4 + 1] = x1;
            s[k * 4 + 2] = x2; s[k * 4 + 3] = x3;
            mx = fmaxf(fmaxf(fmaxf(mx, x0), fmaxf(x1, x2)), x3);
            mn = fminf(fminf(fminf(mn, x0), fminf(x1, x2)), x3);
        }
    }

    // wave butterfly: all lanes end with row max/min
    #pragma unroll
    for (int m = 1; m < 64; m <<= 1) {
        mx = fmaxf(mx, __shfl_xor(mx, m));
        mn = fminf(mn, __shfl_xor(mn, m));
    }

    // ---- 10 iterations of 2-means (exact reference semantics:
    //      tie -> Large; last-iteration cntL used for contrast test)
    float mL = mx, mS = mn;
    float cntL_last = 0.f;
    for (int it = 0; it < 10; ++it) {
        float sumL = 0.f, sumS = 0.f, cntL = 0.f;
        #pragma unroll
        for (int k = 0; k < 8; ++k) {
            const int q = lane + 64 * k;
            if (q < DENSE / 4) {
                #pragma unroll
                for (int r = 0; r < 4; ++r) {
                    const float x  = s[k * 4 + r];
                    const bool  bl = fabsf(x - mL) <= fabsf(x - mS);
                    sumL += bl ? x   : 0.f;
                    cntL += bl ? 1.f : 0.f;
                    sumS += bl ? 0.f : x;
                }
            }
        }
        #pragma unroll
        for (int m = 1; m < 64; m <<= 1) {
            sumL += __shfl_xor(sumL, m);
            sumS += __shfl_xor(sumS, m);
            cntL += __shfl_xor(cntL, m);
        }
        mL = sumL / cntL;
        mS = sumS / ((float)DENSE - cntL);
        cntL_last = cntL;
    }

    if (lane == 0) {
        const bool contrast = ((mL - mS) > 0.005f) && (cntL_last > 5.f);
        const float keep = (validRow && contrast) ? 1.f : 0.f;
        // multiply (not select) so NaN cluster means propagate exactly as in ref
        out[row * 2 + 0] = mL * keep;
        out[row * 2 + 1] = mS * keep;
    }
}

} // namespace

extern "C" void kernel_launch(void* const* d_in, const int* in_sizes, int n_in,
                              void* d_out, int out_size, void* d_ws, size_t ws_size,
                              hipStream_t stream) {
    const float* disp = (const float*)d_in[0];
    const float* fore = (const float*)d_in[1];
    const int*   cx   = (const int*)d_in[2];
    const int*   cy   = (const int*)d_in[3];
    const int*   bx   = (const int*)d_in[4];
    const int*   by   = (const int*)d_in[5];
    float* out = (float*)d_out;

    rsbsp_kernel<<<N, 64, 0, stream>>>(disp, fore, cx, cy, bx, by, out);
}

// Round 2
// 136.771 us; speedup vs baseline: 1.1683x; 1.1683x over previous
//
#include <hip/hip_runtime.h>

namespace {

constexpr int Bn    = 10;
constexpr int H     = 320;
constexpr int W     = 1024;
constexpr int PTS   = 500;
constexpr int DENSE = 2000;
constexpr int N     = Bn * PTS;   // 5000 rows
constexpr int HWp   = H * W;
constexpr int ROWS_PER_BLOCK = 4; // 4 waves per block, 1 row per wave

// 256-thread block = 4 independent waves, one row each. No LDS, no barriers.
__global__ __launch_bounds__(256, 4)
void rsbsp_kernel(const float* __restrict__ disp,
                  const float* __restrict__ forepred,
                  const int*   __restrict__ centerx,
                  const int*   __restrict__ centery,
                  const int*   __restrict__ bx,
                  const int*   __restrict__ by,
                  float*       __restrict__ out)
{
    const int wid  = threadIdx.x >> 6;                  // 0..3
    const int lane = threadIdx.x & 63;                  // 0..63
    const int row  = blockIdx.x * ROWS_PER_BLOCK + wid; // 0..4999
    const int b    = row / PTS;                         // channelInd
    const int cx   = centerx[row];
    const int cy   = centery[row];
    const float* db = disp     + b * HWp;
    const float* fb = forepred + b * HWp;

    // ---- validRow: 3x3 maxpool of |sobel_x(forepred)| at center, * (disp>0.007),
    //      clamp(min=3)-3, > 0.1. Centers are >=11 from all borders, so SAME
    //      padding and the 4-pixel border zeroing are unreachable.
    //      Uniform addresses across the wave -> broadcast loads.
    float F[5][5];
    #pragma unroll
    for (int a = 0; a < 5; ++a)
        #pragma unroll
        for (int c = 0; c < 5; ++c)
            F[a][c] = fb[(cy - 2 + a) * W + (cx - 2 + c)];

    float v = 0.f;
    #pragma unroll
    for (int dy = 0; dy < 3; ++dy)
        #pragma unroll
        for (int dx = 0; dx < 3; ++dx) {
            const float g = (F[dy    ][dx + 2] - F[dy    ][dx])
                    + 2.f * (F[dy + 1][dx + 2] - F[dy + 1][dx])
                    +       (F[dy + 2][dx + 2] - F[dy + 2][dx]);
            v = fmaxf(v, fabsf(g));
        }
    const float dcen = db[cy * W + cx];
    const float mgv  = fmaxf(v * ((dcen > 0.007f) ? 1.f : 0.f), 3.f) - 3.f;
    const bool validRow = mgv > 0.1f;

    // ---- gather 2000 samples; bx/by as int4 (coalesced 16B/lane).
    // Row offset 2000*4B = 8000B stays 16B-aligned.
    const int4* bx4 = reinterpret_cast<const int4*>(bx + row * DENSE);
    const int4* by4 = reinterpret_cast<const int4*>(by + row * DENSE);
    const int cbase = cy * W + cx;

    float s[32];
    float mx = -INFINITY, mn = INFINITY, tot = 0.f;
    #pragma unroll
    for (int k = 0; k < 8; ++k) {
        const int q = lane + 64 * k;            // int4 index, 500 total
        if (q < DENSE / 4) {                     // only k==7 partially masked
            const int4 xb = bx4[q];
            const int4 yb = by4[q];
            const float x0 = db[cbase + yb.x * W + xb.x];
            const float x1 = db[cbase + yb.y * W + xb.y];
            const float x2 = db[cbase + yb.z * W + xb.z];
            const float x3 = db[cbase + yb.w * W + xb.w];
            s[k * 4 + 0] = x0; s[k * 4 + 1] = x1;
            s[k * 4 + 2] = x2; s[k * 4 + 3] = x3;
            mx = fmaxf(fmaxf(fmaxf(mx, x0), fmaxf(x1, x2)), x3);
            mn = fminf(fminf(fminf(mn, x0), fminf(x1, x2)), x3);
            tot += (x0 + x1) + (x2 + x3);
        }
    }

    // wave butterfly: all lanes end with row max/min/total
    #pragma unroll
    for (int m = 1; m < 64; m <<= 1) {
        mx  = fmaxf(mx, __shfl_xor(mx, m));
        mn  = fminf(mn, __shfl_xor(mn, m));
        tot += __shfl_xor(tot, m);
    }

    // ---- 10 iterations of 2-means via midpoint threshold.
    // Invariant mL >= mS, so |x-mL| <= |x-mS|  <=>  x >= (mL+mS)/2
    // (tie -> Large matches reference's `<=`; NaN mid -> all-false matches
    //  reference's NaN-compare-false path). sumS = tot - sumL.
    float mL = mx, mS = mn;
    float cntL_last = 0.f;
    for (int it = 0; it < 10; ++it) {
        const float mid = 0.5f * (mL + mS);
        float sumL = 0.f;
        int   cnt  = 0;
        #pragma unroll
        for (int k = 0; k < 8; ++k) {
            const int q = lane + 64 * k;
            if (q < DENSE / 4) {
                #pragma unroll
                for (int r = 0; r < 4; ++r) {
                    const float x  = s[k * 4 + r];
                    const bool  bl = x >= mid;
                    sumL += bl ? x : 0.f;
                    cnt  += bl ? 1 : 0;
                }
            }
        }
        #pragma unroll
        for (int m = 1; m < 64; m <<= 1) {
            sumL += __shfl_xor(sumL, m);
            cnt  += __shfl_xor(cnt,  m);
        }
        const float cntL = (float)cnt;
        mL = sumL / cntL;
        mS = (tot - sumL) / ((float)DENSE - cntL);
        cntL_last = cntL;
    }

    if (lane == 0) {
        const bool contrast = ((mL - mS) > 0.005f) && (cntL_last > 5.f);
        const float keep = (validRow && contrast) ? 1.f : 0.f;
        // multiply (not select) so NaN cluster means propagate exactly as in ref
        out[row * 2 + 0] = mL * keep;
        out[row * 2 + 1] = mS * keep;
    }
}

} // namespace

extern "C" void kernel_launch(void* const* d_in, const int* in_sizes, int n_in,
                              void* d_out, int out_size, void* d_ws, size_t ws_size,
                              hipStream_t stream) {
    const float* disp = (const float*)d_in[0];
    const float* fore = (const float*)d_in[1];
    const int*   cx   = (const int*)d_in[2];
    const int*   cy   = (const int*)d_in[3];
    const int*   bxp  = (const int*)d_in[4];
    const int*   byp  = (const int*)d_in[5];
    float* out = (float*)d_out;

    rsbsp_kernel<<<N / ROWS_PER_BLOCK, 256, 0, stream>>>(disp, fore, cx, cy, bxp, byp, out);
}

// Round 3
// 136.261 us; speedup vs baseline: 1.1727x; 1.0037x over previous
//
#include <hip/hip_runtime.h>

namespace {

constexpr int Bn    = 10;
constexpr int H     = 320;
constexpr int W     = 1024;
constexpr int PTS   = 500;
constexpr int DENSE = 2000;
constexpr int N     = Bn * PTS;   // 5000 rows
constexpr int HWp   = H * W;
constexpr int RPB   = 4;          // rows (waves) per 256-thread block
constexpr int KITER = 10;

// disp window staged per wave: rows cy-7..cy+7, cols cx-11..cx+12 (padded to 24)
constexpr int WY   = 15;
constexpr int WX   = 24;          // 23 needed, padded to 24; stride 24 spreads all 32 banks
constexpr int WSZ  = WY * WX;     // 360 words = 1440 B per wave
constexpr int WOFF = 7 * WX + 11; // word offset of the center inside the window

// 256-thread block = 4 independent waves, one row each. No barriers (each wave
// touches only its own LDS slice; DS ops are in-order per wave).
__global__ __launch_bounds__(256, 6)
void rsbsp_kernel(const float* __restrict__ disp,
                  const float* __restrict__ forepred,
                  const int*   __restrict__ centerx,
                  const int*   __restrict__ centery,
                  const int*   __restrict__ bx,
                  const int*   __restrict__ by,
                  float*       __restrict__ out)
{
    __shared__ float win[RPB][WSZ];

    const int wid  = threadIdx.x >> 6;
    const int lane = threadIdx.x & 63;
    const int row  = blockIdx.x * RPB + wid;
    const int b    = row / PTS;
    const int cx   = centerx[row];
    const int cy   = centery[row];
    const float* db = disp     + b * HWp;
    const float* fb = forepred + b * HWp;

    // ---- stage the 15x24 disp window into LDS (coalesced, ~6 loads/lane)
    float* wl = win[wid];
    const int gbase = (cy - 7) * W + (cx - 11);
    #pragma unroll
    for (int i = 0; i < 6; ++i) {
        const unsigned w = (unsigned)(lane + 64 * i);
        if (w < WSZ) {
            const unsigned r = w / 24u;       // compiler magic-mul
            const unsigned c = w - r * 24u;   // 0..23 (col cx+12 max: in-bounds, value unused)
            wl[w] = db[gbase + r * W + c];
        }
    }

    // ---- validRow: 3x3 maxpool of |sobel_x(forepred)| at center, * (disp>0.007),
    //      clamp(min=3)-3, > 0.1. Centers are >=11 from all borders, so SAME
    //      padding and the 4-pixel border zeroing are unreachable.
    float F[5][5];
    #pragma unroll
    for (int a = 0; a < 5; ++a)
        #pragma unroll
        for (int c = 0; c < 5; ++c)
            F[a][c] = fb[(cy - 2 + a) * W + (cx - 2 + c)];

    float v = 0.f;
    #pragma unroll
    for (int dy = 0; dy < 3; ++dy)
        #pragma unroll
        for (int dx = 0; dx < 3; ++dx) {
            const float g = (F[dy    ][dx + 2] - F[dy    ][dx])
                    + 2.f * (F[dy + 1][dx + 2] - F[dy + 1][dx])
                    +       (F[dy + 2][dx + 2] - F[dy + 2][dx]);
            v = fmaxf(v, fabsf(g));
        }
    const float dcen = db[cy * W + cx];
    const float mgv  = fmaxf(v * ((dcen > 0.007f) ? 1.f : 0.f), 3.f) - 3.f;
    const bool validRow = mgv > 0.1f;

    // ---- gather 2000 samples from the LDS window; bx/by as int4 (16B/lane)
    const int4* bx4 = reinterpret_cast<const int4*>(bx + row * DENSE);
    const int4* by4 = reinterpret_cast<const int4*>(by + row * DENSE);

    float s[32];
    float mx = -INFINITY, mn = INFINITY, tot = 0.f;
    #pragma unroll
    for (int k = 0; k < 8; ++k) {
        const int q = lane + 64 * k;            // int4 index, 500 total
        if (q < DENSE / 4) {
            const int4 xb = bx4[q];
            const int4 yb = by4[q];
            const float x0 = wl[yb.x * WX + xb.x + WOFF];
            const float x1 = wl[yb.y * WX + xb.y + WOFF];
            const float x2 = wl[yb.z * WX + xb.z + WOFF];
            const float x3 = wl[yb.w * WX + xb.w + WOFF];
            s[k * 4 + 0] = x0; s[k * 4 + 1] = x1;
            s[k * 4 + 2] = x2; s[k * 4 + 3] = x3;
            mx = fmaxf(fmaxf(fmaxf(mx, x0), fmaxf(x1, x2)), x3);
            mn = fminf(fminf(fminf(mn, x0), fminf(x1, x2)), x3);
            tot += (x0 + x1) + (x2 + x3);
        } else {
            // sentinel: compares false against any finite/NaN mid -> never in
            // Large cluster, contributes 0 to sumL/cnt (matches reference).
            s[k * 4 + 0] = -INFINITY; s[k * 4 + 1] = -INFINITY;
            s[k * 4 + 2] = -INFINITY; s[k * 4 + 3] = -INFINITY;
        }
    }

    // wave butterfly: all lanes end with row max/min/total
    #pragma unroll
    for (int m = 1; m < 64; m <<= 1) {
        mx  = fmaxf(mx, __shfl_xor(mx, m));
        mn  = fminf(mn, __shfl_xor(mn, m));
        tot += __shfl_xor(tot, m);
    }

    // ---- 10 iterations of 2-means via midpoint threshold.
    // Invariant mL >= mS, so |x-mL| <= |x-mS| <=> x >= (mL+mS)/2
    // (tie -> Large matches reference's `<=`; NaN mid -> all-false matches
    //  reference's NaN-compare-false path). sumS = tot - sumL.
    // cnt via ballot+popcount: wave-wide by construction (no reduction needed),
    // accumulated on the scalar pipe.
    float mL = mx, mS = mn;
    int cntLast = 0;
    for (int it = 0; it < KITER; ++it) {
        const float mid = 0.5f * (mL + mS);
        float sumL = 0.f;
        int   cnt  = 0;
        #pragma unroll
        for (int j = 0; j < 32; ++j) {
            const float x  = s[j];
            const bool  bl = x >= mid;
            sumL += bl ? x : 0.f;
            cnt  += (int)__popcll(__ballot(bl));
        }
        #pragma unroll
        for (int m = 1; m < 64; m <<= 1) sumL += __shfl_xor(sumL, m);

        const float cf = (float)cnt;
        const float df = (float)DENSE - cf;
        if (it < KITER - 1) {
            // fast rcp (~1e-7 rel err) for intermediate iterations
            mL = sumL * __builtin_amdgcn_rcpf(cf);
            mS = (tot - sumL) * __builtin_amdgcn_rcpf(df);
        } else {
            // exact division for the output iteration
            mL = sumL / cf;
            mS = (tot - sumL) / df;
        }
        // cnt==0: sumL is exactly +0 -> mL = NaN (matches ref 0/0).
        // cnt==DENSE: ref gives 0/0=NaN; (tot-sumL) may be ±eps -> force NaN.
        if (cnt == DENSE) mS = __int_as_float(0x7fc00000);
        cntLast = cnt;
    }

    if (lane == 0) {
        const bool contrast = ((mL - mS) > 0.005f) && (cntLast > 5);
        const float keep = (validRow && contrast) ? 1.f : 0.f;
        // multiply (not select) so NaN cluster means propagate exactly as in ref
        out[row * 2 + 0] = mL * keep;
        out[row * 2 + 1] = mS * keep;
    }
}

} // namespace

extern "C" void kernel_launch(void* const* d_in, const int* in_sizes, int n_in,
                              void* d_out, int out_size, void* d_ws, size_t ws_size,
                              hipStream_t stream) {
    const float* disp = (const float*)d_in[0];
    const float* fore = (const float*)d_in[1];
    const int*   cx   = (const int*)d_in[2];
    const int*   cy   = (const int*)d_in[3];
    const int*   bxp  = (const int*)d_in[4];
    const int*   byp  = (const int*)d_in[5];
    float* out = (float*)d_out;

    rsbsp_kernel<<<N / RPB, 256, 0, stream>>>(disp, fore, cx, cy, bxp, byp, out);
}

// Round 4
// 125.354 us; speedup vs baseline: 1.2747x; 1.0870x over previous
//
#include <hip/hip_runtime.h>

namespace {

constexpr int Bn    = 10;
constexpr int H     = 320;
constexpr int W     = 1024;
constexpr int PTS   = 500;
constexpr int DENSE = 2000;
constexpr int N     = Bn * PTS;   // 5000 rows
constexpr int HWp   = H * W;
constexpr int KITER = 10;

// disp window: rows cy-7..cy+7, cols cx-11..cx+12 (padded to 24)
constexpr int WY   = 15;
constexpr int WX   = 24;
constexpr int WSZ  = WY * WX;       // 360 words
constexpr int WOFF = 7 * WX + 11;   // center offset inside the window

// One block (256 thr = 4 waves) per row. Validity computed cooperatively;
// invalid rows write zeros and exit before touching bx/by (80 MB stream).
__global__ __launch_bounds__(256, 8)
void rsbsp_kernel(const float* __restrict__ disp,
                  const float* __restrict__ forepred,
                  const int*   __restrict__ centerx,
                  const int*   __restrict__ centery,
                  const int*   __restrict__ bx,
                  const int*   __restrict__ by,
                  float*       __restrict__ out)
{
    __shared__ float ldsF[25];      // 5x5 forepred patch
    __shared__ float ldsG[9];       // |sobel_x| at the 9 maxpool taps
    __shared__ float win[WSZ];      // 15x24 disp window
    __shared__ float cmb0[4][3];    // per-wave {mx, mn, tot}
    __shared__ float cmb[2][4][2];  // [parity][wave][{sumL, cnt}]

    const int t   = threadIdx.x;
    const int wid = t >> 6;
    const int row = blockIdx.x;     // 0..4999
    const int b   = row / PTS;
    const int cx  = centerx[row];
    const int cy  = centery[row];
    const float* db = disp     + b * HWp;
    const float* fb = forepred + b * HWp;

    // ---- issue all validity + window loads up front (latency overlap)
    const float dcen = db[cy * W + cx];

    float fpix = 0.f;
    if (t < 25) {
        const int r = t / 5, c = t % 5;
        fpix = fb[(cy - 2 + r) * W + (cx - 2 + c)];
    }
    // Window staging is ~1.4 KB/row (L3-resident disp) -> always stage;
    // it overlaps the validity computation.
    const int gbase = (cy - 7) * W + (cx - 11);
    float w0, w1 = 0.f;
    {
        const unsigned r0 = (unsigned)t / 24u, c0 = (unsigned)t - r0 * 24u;
        w0 = db[gbase + r0 * W + c0];               // t<256<360: all active
        const int i1 = t + 256;
        if (i1 < WSZ) {
            const unsigned r1 = (unsigned)i1 / 24u, c1 = (unsigned)i1 - r1 * 24u;
            w1 = db[gbase + r1 * W + c1];
        }
    }
    if (t < 25) ldsF[t] = fpix;
    win[t] = w0;
    if (t + 256 < WSZ) win[t + 256] = w1;
    __syncthreads();

    // ---- validity: 3x3 maxpool of |sobel_x(forepred)| at center, *(disp>0.007),
    //      clamp(min=3)-3 > 0.1. Centers >=11 from borders: SAME padding and the
    //      4-pixel border zeroing are unreachable.
    if (t < 9) {
        const int dy = t / 3, dx = t % 3;
        const float g =
                  (ldsF[(dy    ) * 5 + dx + 2] - ldsF[(dy    ) * 5 + dx])
           + 2.f * (ldsF[(dy + 1) * 5 + dx + 2] - ldsF[(dy + 1) * 5 + dx])
           +       (ldsF[(dy + 2) * 5 + dx + 2] - ldsF[(dy + 2) * 5 + dx]);
        ldsG[t] = fabsf(g);
    }
    __syncthreads();

    float v = 0.f;
    #pragma unroll
    for (int j = 0; j < 9; ++j) v = fmaxf(v, ldsG[j]);
    const float mgv = fmaxf(v * ((dcen > 0.007f) ? 1.f : 0.f), 3.f) - 3.f;
    const bool validRow = mgv > 0.1f;

    if (!validRow) {
        // Reference: out = km * keep with keep=0; km is provably finite here
        // (Large cluster always holds the max sample), so exact zeros match.
        if (t == 0) { out[row * 2 + 0] = 0.f; out[row * 2 + 1] = 0.f; }
        return;
    }

    // ---- gather 2000 samples (8/lane) from the LDS window; bx/by as int4
    const int4* bx4 = reinterpret_cast<const int4*>(bx + row * DENSE);
    const int4* by4 = reinterpret_cast<const int4*>(by + row * DENSE);

    float s[8];
    float mx = -INFINITY, mn = INFINITY, tot = 0.f;
    #pragma unroll
    for (int k = 0; k < 2; ++k) {
        const int q = t + 256 * k;              // int4 index, 500 total
        if (q < DENSE / 4) {
            const int4 xb = bx4[q];
            const int4 yb = by4[q];
            const float x0 = win[yb.x * WX + xb.x + WOFF];
            const float x1 = win[yb.y * WX + xb.y + WOFF];
            const float x2 = win[yb.z * WX + xb.z + WOFF];
            const float x3 = win[yb.w * WX + xb.w + WOFF];
            s[k * 4 + 0] = x0; s[k * 4 + 1] = x1;
            s[k * 4 + 2] = x2; s[k * 4 + 3] = x3;
            mx = fmaxf(fmaxf(fmaxf(mx, x0), fmaxf(x1, x2)), x3);
            mn = fminf(fminf(fminf(mn, x0), fminf(x1, x2)), x3);
            tot += (x0 + x1) + (x2 + x3);
        } else {
            // -INF sentinel: never >= mid (finite or NaN) -> contributes
            // nothing to Large cluster, exactly like absent samples.
            s[k * 4 + 0] = -INFINITY; s[k * 4 + 1] = -INFINITY;
            s[k * 4 + 2] = -INFINITY; s[k * 4 + 3] = -INFINITY;
        }
    }

    // wave butterfly then cross-wave LDS combine for {mx, mn, tot}
    #pragma unroll
    for (int m = 1; m < 64; m <<= 1) {
        mx  = fmaxf(mx, __shfl_xor(mx, m));
        mn  = fminf(mn, __shfl_xor(mn, m));
        tot += __shfl_xor(tot, m);
    }
    if ((t & 63) == 0) { cmb0[wid][0] = mx; cmb0[wid][1] = mn; cmb0[wid][2] = tot; }
    __syncthreads();
    mx  = fmaxf(fmaxf(cmb0[0][0], cmb0[1][0]), fmaxf(cmb0[2][0], cmb0[3][0]));
    mn  = fminf(fminf(cmb0[0][1], cmb0[1][1]), fminf(cmb0[2][1], cmb0[3][1]));
    tot = (cmb0[0][2] + cmb0[1][2]) + (cmb0[2][2] + cmb0[3][2]);

    // ---- 2-means via midpoint threshold (mL>=mS invariant: |x-mL|<=|x-mS|
    //      <=> x>=mid; tie->Large matches `<=`; NaN mid -> all-false matches
    //      the reference's NaN-compare path). sumS = tot - sumL.
    //      Convergence exit: (cnt,sumL) repeating is a fixed point -> all
    //      remaining iterations are bit-identical; finalize with exact div.
    float mL = mx, mS = mn;
    float cntLast = 0.f;
    float prevSum = -1.f, prevCnt = -1.f;   // unreachable sentinels
    #pragma unroll 1
    for (int it = 0; it < KITER; ++it) {
        const float mid = 0.5f * (mL + mS);
        float sumL = 0.f;
        int   cw   = 0;
        #pragma unroll
        for (int j = 0; j < 8; ++j) {
            const float x  = s[j];
            const bool  bl = x >= mid;
            sumL += bl ? x : 0.f;
            cw   += (int)__popcll(__ballot(bl));   // wave-wide count, SALU
        }
        #pragma unroll
        for (int m = 1; m < 64; m <<= 1) sumL += __shfl_xor(sumL, m);

        const int par = it & 1;                    // parity dbuf: 1 barrier/iter
        if ((t & 63) == 0) { cmb[par][wid][0] = sumL; cmb[par][wid][1] = (float)cw; }
        __syncthreads();
        sumL = (cmb[par][0][0] + cmb[par][1][0]) + (cmb[par][2][0] + cmb[par][3][0]);
        const float cf = (cmb[par][0][1] + cmb[par][1][1]) + (cmb[par][2][1] + cmb[par][3][1]);
        const float df = (float)DENSE - cf;

        const bool done = (it == KITER - 1) || (cf == prevCnt && sumL == prevSum);
        if (done) {
            mL = sumL / cf;                        // exact div for outputs
            mS = (tot - sumL) / df;
            // cnt==0: sumL=+0 -> 0/0=NaN matches ref. cnt==DENSE: force NaN
            // (tot-sumL may be +-eps -> +-inf otherwise).
            if (cf == (float)DENSE) mS = __int_as_float(0x7fc00000);
            cntLast = cf;
            break;
        }
        mL = sumL * __builtin_amdgcn_rcpf(cf);     // fast rcp for intermediates
        mS = (tot - sumL) * __builtin_amdgcn_rcpf(df);
        prevSum = sumL; prevCnt = cf;
    }

    if (t == 0) {
        const bool contrast = ((mL - mS) > 0.005f) && (cntLast > 5.f);
        const float keep = contrast ? 1.f : 0.f;   // validRow already true
        // multiply (not select) so NaN cluster means propagate as in ref
        out[row * 2 + 0] = mL * keep;
        out[row * 2 + 1] = mS * keep;
    }
}

} // namespace

extern "C" void kernel_launch(void* const* d_in, const int* in_sizes, int n_in,
                              void* d_out, int out_size, void* d_ws, size_t ws_size,
                              hipStream_t stream) {
    const float* disp = (const float*)d_in[0];
    const float* fore = (const float*)d_in[1];
    const int*   cx   = (const int*)d_in[2];
    const int*   cy   = (const int*)d_in[3];
    const int*   bxp  = (const int*)d_in[4];
    const int*   byp  = (const int*)d_in[5];
    float* out = (float*)d_out;

    rsbsp_kernel<<<N, 256, 0, stream>>>(disp, fore, cx, cy, bxp, byp, out);
}